// Round 5
// baseline (299.588 us; speedup 1.0000x reference)
//
#include <hip/hip_runtime.h>
#include <hip/hip_bf16.h>
#include <stdint.h>

// ---- problem constants ----
#define BATCH 4
#define SEQ   8400
#define DM    512
#define KP    8484      // SEQ + 2*42 (edge pad)
#define NWIN  100
#define STEP_ 84
#define PAD_  42
#define NKEY  126
#define MROWS 33600     // BATCH*SEQ

typedef __attribute__((ext_vector_type(8))) short short8;
typedef __attribute__((ext_vector_type(4))) float float4v;
typedef __attribute__((ext_vector_type(4))) unsigned short ushort4v;

#define MFMA16 __builtin_amdgcn_mfma_f32_16x16x32_bf16

__device__ __forceinline__ unsigned short f2bf(float f) {
    union { float f; unsigned u; } v; v.f = f;
    return (unsigned short)((v.u + 0x7FFFu + ((v.u >> 16) & 1u)) >> 16);  // RNE
}
__device__ __forceinline__ unsigned short bfc(float f) {
    __hip_bfloat16 h = __float2bfloat16(f);
    union { __hip_bfloat16 h; unsigned short u; } v; v.h = h;
    return v.u;
}

typedef __attribute__((address_space(1))) const unsigned int as1_cu32;
typedef __attribute__((address_space(3))) unsigned int as3_u32;
__device__ __forceinline__ void gload16(const void* g, void* l) {
    __builtin_amdgcn_global_load_lds((as1_cu32*)g, (as3_u32*)l, 16, 0, 0);
}

// ============ prepass: W (f32 [k][n] 512x512) -> Wt (bf16 [n][k]) ============
__global__ __launch_bounds__(256) void kprep(const float* __restrict__ Wq,
                                             const float* __restrict__ Wk,
                                             const float* __restrict__ Wv,
                                             const float* __restrict__ Wo,
                                             unsigned short* __restrict__ Wt) {
    const float* src = blockIdx.z == 0 ? Wq : blockIdx.z == 1 ? Wk
                     : blockIdx.z == 2 ? Wv : Wo;
    unsigned short* dst = Wt + (size_t)blockIdx.z * DM * DM;
    __shared__ float t[64][65];
    int c = threadIdx.x & 63, r4 = threadIdx.x >> 6;
    int kb = blockIdx.x * 64, nb = blockIdx.y * 64;
    for (int i = 0; i < 16; i++) {
        int r = r4 * 16 + i;
        t[r][c] = src[(size_t)(kb + r) * DM + nb + c];
    }
    __syncthreads();
    for (int i = 0; i < 16; i++) {
        int r = r4 * 16 + i;
        dst[(size_t)(nb + r) * DM + kb + c] = f2bf(t[c][r]);
    }
}

// ============ kernel 1: fused pad+cvt+QKV projection =========================
// m97 structure: BM=128, BN=128, BK=64, 4 waves, 2-barrier, single LDS buffer.
// A: f32 (pad-gather) reg-staged -> bf16 LDS (cvt once per element).
// B: bf16 W^T via global_load_lds (pre-swizzled source, linear dest).
// Q/K out: [h*B+b][p][64]; V out transposed: VT[h*B+b][d][p].
__global__ __launch_bounds__(256) void kproj(const float* __restrict__ q,
                                             const float* __restrict__ k,
                                             const float* __restrict__ v,
                                             const unsigned short* __restrict__ Wt,
                                             const float* __restrict__ bq,
                                             const float* __restrict__ bk,
                                             const float* __restrict__ bv,
                                             unsigned short* __restrict__ Qb,
                                             unsigned short* __restrict__ Kb,
                                             unsigned short* __restrict__ VT) {
    int mt = blockIdx.x, nt = blockIdx.y, z = blockIdx.z;
    int ten = z >> 2, b = z & 3;
    const float* A = (ten == 0 ? q : ten == 1 ? k : v) + (size_t)b * SEQ * DM;
    const unsigned short* W = Wt + (size_t)ten * DM * DM;
    const float* bias = ten == 0 ? bq : ten == 1 ? bk : bv;
    float scale = ten == 0 ? 0.07715167498104595f : 1.f;   // 1/sqrt(168)
    int m0 = mt * 128, n0 = nt * 128;

    // [0,16K) Al bf16 [128][64] swz; [16K,32K) Bl bf16 [128][64] swz;
    // whole [0,34816) reused as epilogue bounce [128][136] u16.
    __shared__ __align__(16) char lds[34816];
    char* Al = lds;
    char* Bl = lds + 16384;

    int tid = threadIdx.x, lane = tid & 63, w = tid >> 6;
    int wm = (w >> 1) * 64, wn = (w & 1) * 64;
    int l15 = lane & 15, g = lane >> 4;

    // A-stage indices (fixed per thread): 4 threads per row, 16 f32 each
    int ar4 = tid >> 2;              // 0..63
    int ac = tid & 3;                // col group: 16 f32 at ac*16
    int c0 = ac * 2;                 // bf16 chunk index base (2 chunks of 8)

    float4v acc[4][4];
#pragma unroll
    for (int i = 0; i < 4; i++)
#pragma unroll
        for (int j = 0; j < 4; j++) { float4v zz = {0.f,0.f,0.f,0.f}; acc[i][j] = zz; }

    for (int kt = 0; kt < 8; kt++) {
        // --- B: 128 rows x 8 chunks, gload_lds w/ pre-swizzled source
#pragma unroll
        for (int it = 0; it < 4; it++) {
            int c = it * 256 + tid;
            int r = c >> 3;
            int kg = (c & 7) ^ (r & 7);
            gload16(W + (size_t)(n0 + r) * DM + kt * 64 + kg * 8, Bl + c * 16);
        }
        // --- A: f32 load + cvt + swizzled ds_write_b128 (2 rows per thread)
#pragma unroll
        for (int it = 0; it < 2; it++) {
            int rr = it * 64 + ar4;
            int p = m0 + rr;
            int row = p - PAD_; row = row < 0 ? 0 : (row > SEQ - 1 ? SEQ - 1 : row);
            const float* src = A + (size_t)row * DM + kt * 64 + ac * 16;
            float4v f0 = *(const float4v*)(src);
            float4v f1 = *(const float4v*)(src + 4);
            float4v f2 = *(const float4v*)(src + 8);
            float4v f3 = *(const float4v*)(src + 12);
            short8 h0, h1;
            h0[0] = (short)bfc(f0.x); h0[1] = (short)bfc(f0.y);
            h0[2] = (short)bfc(f0.z); h0[3] = (short)bfc(f0.w);
            h0[4] = (short)bfc(f1.x); h0[5] = (short)bfc(f1.y);
            h0[6] = (short)bfc(f1.z); h0[7] = (short)bfc(f1.w);
            h1[0] = (short)bfc(f2.x); h1[1] = (short)bfc(f2.y);
            h1[2] = (short)bfc(f2.z); h1[3] = (short)bfc(f2.w);
            h1[4] = (short)bfc(f3.x); h1[5] = (short)bfc(f3.y);
            h1[6] = (short)bfc(f3.z); h1[7] = (short)bfc(f3.w);
            *(short8*)(Al + rr * 128 + ((c0 ^ (rr & 7)) << 4)) = h0;
            *(short8*)(Al + rr * 128 + (((c0 + 1) ^ (rr & 7)) << 4)) = h1;
        }
        __syncthreads();
#pragma unroll
        for (int ks = 0; ks < 2; ks++) {
            short8 af[4], bfr[4];
#pragma unroll
            for (int i = 0; i < 4; i++) {
                int r = wm + i * 16 + l15, kg = ks * 4 + g;
                af[i] = *(const short8*)(Al + r * 128 + ((kg ^ (r & 7)) << 4));
            }
#pragma unroll
            for (int j = 0; j < 4; j++) {
                int r = wn + j * 16 + l15, kg = ks * 4 + g;
                bfr[j] = *(const short8*)(Bl + r * 128 + ((kg ^ (r & 7)) << 4));
            }
#pragma unroll
            for (int i = 0; i < 4; i++)
#pragma unroll
                for (int j = 0; j < 4; j++)
                    acc[i][j] = MFMA16(af[i], bfr[j], acc[i][j], 0, 0, 0);
        }
        __syncthreads();
    }

    if (ten <= 1) {
        // bounce [128][136] u16 then coalesced short8 head-split writes
        unsigned short* Ol = (unsigned short*)lds;
#pragma unroll
        for (int j = 0; j < 4; j++) {
            int nl = wn + j * 16 + l15;
            float bval = bias[n0 + nl];
#pragma unroll
            for (int i = 0; i < 4; i++) {
                float4v vv = acc[i][j];
#pragma unroll
                for (int r = 0; r < 4; r++)
                    Ol[(wm + i * 16 + g * 4 + r) * 136 + nl] =
                        f2bf((vv[r] + bval) * scale);
            }
        }
        __syncthreads();
        unsigned short* O = ten == 0 ? Qb : Kb;
        int hbase = n0 >> 6;
        for (int c = tid; c < 2048; c += 256) {        // 128 rows x 16 chunks
            int row = c >> 4, chunk = c & 15;
            int p = m0 + row;
            if (p < KP) {
                int h = hbase + (chunk >> 3), ch = chunk & 7;
                *(short8*)(O + ((size_t)(h * BATCH + b) * KP + p) * 64 + ch * 8) =
                    *(const short8*)(Ol + row * 136 + chunk * 8);
            }
        }
    } else {
        // V: direct transposed stores VT[hb][d][p] (lane has 4 consecutive p)
#pragma unroll
        for (int j = 0; j < 4; j++) {
            int n = n0 + wn + j * 16 + l15;
            float bval = bias[n];
            int h = n >> 6, d = n & 63;
            unsigned short* base = VT + ((size_t)(h * BATCH + b) * 64 + d) * KP;
#pragma unroll
            for (int i = 0; i < 4; i++) {
                int p = m0 + wm + i * 16 + g * 4;
                if (p <= KP - 4) {
                    float4v vv = acc[i][j];
                    ushort4v wv;
                    wv[0] = f2bf(vv.x + bval); wv[1] = f2bf(vv.y + bval);
                    wv[2] = f2bf(vv.z + bval); wv[3] = f2bf(vv.w + bval);
                    *(ushort4v*)(base + p) = wv;
                }
            }
        }
    }
}

// ============ kernel 2: windowed causal attention ============================
__global__ __launch_bounds__(384) void kattn(const unsigned short* __restrict__ Qb,
                                             const unsigned short* __restrict__ Kb,
                                             const unsigned short* __restrict__ VT,
                                             unsigned short* __restrict__ attn) {
    int win = blockIdx.x, hb = blockIdx.y;
    int h = hb >> 2, b = hb & 3;
    const unsigned short* Qg = Qb + (size_t)hb * KP * 64;
    const unsigned short* Kg = Kb + (size_t)hb * KP * 64;
    const unsigned short* Vt = VT + (size_t)hb * 64 * KP;
    int p0 = win * STEP_;

    // Ql [0,12288) 96x64; Kl [12288,28672) 128x64; Vl [28672,45056) 64x128;
    // Pl [45056,69632) 96x128. Ol reuses Ql.
    __shared__ __align__(16) char lds[69632];

    int tid = threadIdx.x, lane = tid & 63, f = tid >> 6;
    int l15 = lane & 15, g = lane >> 4;

#pragma unroll
    for (int it = 0; it < 5; it++) {
        int base = it * 384 + f * 64;
        if (base < 768) {                       // Q chunks
            int c = base + lane;
            int qi = c >> 3, kg = (c & 7) ^ (qi & 7);
            gload16(Qg + (size_t)(p0 + PAD_ + qi) * 64 + kg * 8, lds + base * 16);
        } else if (base < 1792) {               // K chunks
            int c = base + lane - 768;
            int x = c >> 3, kg = (c & 7) ^ (x & 7);
            gload16(Kg + (size_t)(p0 + x) * 64 + kg * 8, lds + base * 16);
        }
    }
    for (int c = tid; c < 2048; c += 384) {
        int d = c >> 5, c2 = c & 31;
        ushort4v wv = *(const ushort4v*)(Vt + (size_t)d * KP + p0 + c2 * 4);
        int cx = c2 >> 1;
        *(ushort4v*)(lds + 28672 + d * 256 + (((cx ^ (d & 7)) << 4) | ((c2 & 1) * 8))) = wv;
    }
    __syncthreads();

    short8 bq2[2];
    {
        int r = f * 16 + l15;
#pragma unroll
        for (int ks = 0; ks < 2; ks++) {
            int kg = ks * 4 + g;
            bq2[ks] = *(const short8*)(lds + r * 128 + ((kg ^ (r & 7)) << 4));
        }
    }
    float4v st[8];
#pragma unroll
    for (int xf = 0; xf < 8; xf++) {
        float4v zz = {0.f,0.f,0.f,0.f}; st[xf] = zz;
#pragma unroll
        for (int ks = 0; ks < 2; ks++) {
            int r = xf * 16 + l15;
            int kg = ks * 4 + g;
            short8 a = *(const short8*)(lds + 12288 + r * 128 + ((kg ^ (r & 7)) << 4));
            st[xf] = MFMA16(a, bq2[ks], st[xf], 0, 0, 0);
        }
    }

    int w_abs = PAD_ + f * 16 + l15;
    int w_eff = w_abs > 125 ? 125 : w_abs;
    float mx = -1e30f;
#pragma unroll
    for (int xf = 0; xf < 8; xf++)
#pragma unroll
        for (int r = 0; r < 4; r++) {
            int x = xf * 16 + g * 4 + r;
            float vv = st[xf][r];
            if (x > w_eff) vv = -1e30f;
            st[xf][r] = vv;
            mx = fmaxf(mx, vv);
        }
    mx = fmaxf(mx, __shfl_xor(mx, 16));
    mx = fmaxf(mx, __shfl_xor(mx, 32));
    float s = 0.f;
#pragma unroll
    for (int xf = 0; xf < 8; xf++)
#pragma unroll
        for (int r = 0; r < 4; r++) {
            float e = __expf(st[xf][r] - mx);
            st[xf][r] = e;
            s += e;
        }
    s += __shfl_xor(s, 16);
    s += __shfl_xor(s, 32);
    float inv = 1.f / s;

    {
        int qi = f * 16 + l15;
#pragma unroll
        for (int xf = 0; xf < 8; xf++) {
            ushort4v pw;
#pragma unroll
            for (int r = 0; r < 4; r++) pw[r] = f2bf(st[xf][r] * inv);
            int xc = 2 * xf + (g >> 1);
            *(ushort4v*)(lds + 45056 + qi * 256 + ((xc ^ (qi & 7)) << 4) + (g & 1) * 8) = pw;
        }
    }
    __syncthreads();

    float4v pv[4];
#pragma unroll
    for (int j = 0; j < 4; j++) { float4v zz = {0.f,0.f,0.f,0.f}; pv[j] = zz; }
    int qi = f * 16 + l15;
#pragma unroll
    for (int g2 = 0; g2 < 4; g2++) {
        int xc = g2 * 4 + g;
        short8 a = *(const short8*)(lds + 45056 + qi * 256 + ((xc ^ (qi & 7)) << 4));
#pragma unroll
        for (int j = 0; j < 4; j++) {
            int d = j * 16 + l15;
            short8 bvv = *(const short8*)(lds + 28672 + d * 256 + ((xc ^ (d & 7)) << 4));
            pv[j] = MFMA16(a, bvv, pv[j], 0, 0, 0);
        }
    }

    unsigned short* Ol = (unsigned short*)lds;
#pragma unroll
    for (int j = 0; j < 4; j++) {
        int d = j * 16 + l15;
#pragma unroll
        for (int r = 0; r < 4; r++) {
            int qq = f * 16 + g * 4 + r;
            int byte = qq * 128 + ((((d >> 3) ^ (qq & 7))) << 4) + (d & 7) * 2;
            *(unsigned short*)((char*)Ol + byte) = f2bf(pv[j][r]);
        }
    }
    __syncthreads();
    for (int c = tid; c < 672; c += 384) {
        int qq = c >> 3, ch = c & 7;
        short8 hv = *(const short8*)((char*)Ol + qq * 128 + ((ch ^ (qq & 7)) << 4));
        size_t off = ((size_t)(b * SEQ + win * STEP_ + qq) * DM) + h * 64 + ch * 8;
        *(short8*)(attn + off) = hv;
    }
}

// ============ kernel 3: output projection, m97 128x128x64 ====================
__global__ __launch_bounds__(256) void kout(const unsigned short* __restrict__ Ab,
                                            const unsigned short* __restrict__ W,
                                            const float* __restrict__ bias,
                                            float* __restrict__ Out) {
    int m0 = blockIdx.x * 128, n0 = blockIdx.y * 128;
    __shared__ __align__(16) char lds[32768];
    char* Al = lds;
    char* Bl = lds + 16384;
    int tid = threadIdx.x, lane = tid & 63, w = tid >> 6;
    int wm = (w >> 1) * 64, wn = (w & 1) * 64;
    int l15 = lane & 15, g = lane >> 4;

    float4v acc[4][4];
#pragma unroll
    for (int i = 0; i < 4; i++)
#pragma unroll
        for (int j = 0; j < 4; j++) { float4v zz = {0.f,0.f,0.f,0.f}; acc[i][j] = zz; }

    for (int kt = 0; kt < 8; kt++) {
#pragma unroll
        for (int it = 0; it < 4; it++) {
            int c = it * 256 + tid;
            int r = c >> 3;
            int kg = (c & 7) ^ (r & 7);
            int row = m0 + r; if (row > MROWS - 1) row = MROWS - 1;
            gload16(Ab + (size_t)row * DM + kt * 64 + kg * 8, Al + c * 16);
        }
#pragma unroll
        for (int it = 0; it < 4; it++) {
            int c = it * 256 + tid;
            int r = c >> 3;
            int kg = (c & 7) ^ (r & 7);
            gload16(W + (size_t)(n0 + r) * DM + kt * 64 + kg * 8, Bl + c * 16);
        }
        __syncthreads();
#pragma unroll
        for (int ks = 0; ks < 2; ks++) {
            short8 af[4], bfr[4];
#pragma unroll
            for (int i = 0; i < 4; i++) {
                int r = wm + i * 16 + l15, kg = ks * 4 + g;
                af[i] = *(const short8*)(Al + r * 128 + ((kg ^ (r & 7)) << 4));
            }
#pragma unroll
            for (int j = 0; j < 4; j++) {
                int r = wn + j * 16 + l15, kg = ks * 4 + g;
                bfr[j] = *(const short8*)(Bl + r * 128 + ((kg ^ (r & 7)) << 4));
            }
#pragma unroll
            for (int i = 0; i < 4; i++)
#pragma unroll
                for (int j = 0; j < 4; j++)
                    acc[i][j] = MFMA16(af[i], bfr[j], acc[i][j], 0, 0, 0);
        }
        __syncthreads();
    }
#pragma unroll
    for (int j = 0; j < 4; j++) {
        int n = n0 + wn + j * 16 + l15;
        float bv = bias[n];
#pragma unroll
        for (int i = 0; i < 4; i++) {
            float4v vv = acc[i][j];
#pragma unroll
            for (int r = 0; r < 4; r++) {
                int m = m0 + wm + i * 16 + g * 4 + r;
                if (m < MROWS) Out[(size_t)m * DM + n] = vv[r] + bv;
            }
        }
    }
}

// ============ launch =========================================================
extern "C" void kernel_launch(void* const* d_in, const int* in_sizes, int n_in,
                              void* d_out, int out_size, void* d_ws, size_t ws_size,
                              hipStream_t stream) {
    const float* q  = (const float*)d_in[0];
    const float* k  = (const float*)d_in[1];
    const float* v  = (const float*)d_in[2];
    const float* Wq = (const float*)d_in[3];
    const float* bq = (const float*)d_in[4];
    const float* Wk = (const float*)d_in[5];
    const float* bk = (const float*)d_in[6];
    const float* Wv = (const float*)d_in[7];
    const float* bv = (const float*)d_in[8];
    const float* Wo = (const float*)d_in[9];
    const float* bo = (const float*)d_in[10];

    const size_t WT_ELEMS  = (size_t)4 * DM * DM;
    const size_t QKV_ELEMS = (size_t)32 * KP * 64;
    const size_t ATT_ELEMS = (size_t)MROWS * DM;
    size_t need = (WT_ELEMS + 3 * QKV_ELEMS + ATT_ELEMS) * 2;
    if (ws_size < need) return;

    unsigned short* Wt = (unsigned short*)d_ws;
    unsigned short* Qb = Wt + WT_ELEMS;
    unsigned short* Kb = Qb + QKV_ELEMS;
    unsigned short* VT = Kb + QKV_ELEMS;
    unsigned short* Ab = VT + QKV_ELEMS;

    kprep<<<dim3(8, 8, 4), dim3(256), 0, stream>>>(Wq, Wk, Wv, Wo, Wt);
    kproj<<<dim3(67, 4, 12), dim3(256), 0, stream>>>(q, k, v, Wt, bq, bk, bv,
                                                     Qb, Kb, VT);
    kattn<<<dim3(NWIN, 32), dim3(384), 0, stream>>>(Qb, Kb, VT, Ab);
    kout<<<dim3(263, 4), dim3(256), 0, stream>>>(Ab, Wt + 3 * DM * DM, bo,
                                                 (float*)d_out);
}

// Round 6
// 252.503 us; speedup vs baseline: 1.1865x; 1.1865x over previous
//
#include <hip/hip_runtime.h>
#include <hip/hip_bf16.h>
#include <stdint.h>

// ---- problem constants ----
#define BATCH 4
#define SEQ   8400
#define DM    512
#define KP    8484      // SEQ + 2*42 (edge pad)
#define NWIN  100
#define STEP_ 84
#define PAD_  42
#define NKEY  126
#define MROWS 33600     // BATCH*SEQ

typedef __attribute__((ext_vector_type(8))) short short8;
typedef __attribute__((ext_vector_type(4))) float float4v;
typedef __attribute__((ext_vector_type(4))) unsigned short ushort4v;

#define MFMA16 __builtin_amdgcn_mfma_f32_16x16x32_bf16

__device__ __forceinline__ unsigned short f2bf(float f) {
    union { float f; unsigned u; } v; v.f = f;
    return (unsigned short)((v.u + 0x7FFFu + ((v.u >> 16) & 1u)) >> 16);  // RNE
}
__device__ __forceinline__ unsigned short bfc(float f) {
    __hip_bfloat16 h = __float2bfloat16(f);
    union { __hip_bfloat16 h; unsigned short u; } v; v.h = h;
    return v.u;
}

typedef __attribute__((address_space(1))) const unsigned int as1_cu32;
typedef __attribute__((address_space(3))) unsigned int as3_u32;
__device__ __forceinline__ void gload16(const void* g, void* l) {
    __builtin_amdgcn_global_load_lds((as1_cu32*)g, (as3_u32*)l, 16, 0, 0);
}

// ============ prepass: W (f32 [k][n] 512x512) -> Wt (bf16 [n][k]) ============
__global__ __launch_bounds__(256) void kprep(const float* __restrict__ Wq,
                                             const float* __restrict__ Wk,
                                             const float* __restrict__ Wv,
                                             const float* __restrict__ Wo,
                                             unsigned short* __restrict__ Wt) {
    const float* src = blockIdx.z == 0 ? Wq : blockIdx.z == 1 ? Wk
                     : blockIdx.z == 2 ? Wv : Wo;
    unsigned short* dst = Wt + (size_t)blockIdx.z * DM * DM;
    __shared__ float t[64][65];
    int c = threadIdx.x & 63, r4 = threadIdx.x >> 6;
    int kb = blockIdx.x * 64, nb = blockIdx.y * 64;
    for (int i = 0; i < 16; i++) {
        int r = r4 * 16 + i;
        t[r][c] = src[(size_t)(kb + r) * DM + nb + c];
    }
    __syncthreads();
    for (int i = 0; i < 16; i++) {
        int r = r4 * 16 + i;
        dst[(size_t)(nb + r) * DM + kb + c] = f2bf(t[c][r]);
    }
}

// ============ kernel 1: fused pad+cvt+QKV projection =========================
// BM=64, BN=512 (A read ONCE), BK=64, 512 threads = 8 waves (1x8), 2-barrier.
// A: f32 pad-gather reg-staged -> bf16 LDS (8 KB). B: gload_lds (64 KB).
// LDS 72 KB -> 2 blocks/CU -> 16 waves/CU.
// Q/K out: [h*B+b][p][64]; V out transposed: VT[h*B+b][d][p].
__global__ __launch_bounds__(512, 4) void kproj(const float* __restrict__ q,
                                                const float* __restrict__ k,
                                                const float* __restrict__ v,
                                                const unsigned short* __restrict__ Wt,
                                                const float* __restrict__ bq,
                                                const float* __restrict__ bk,
                                                const float* __restrict__ bv,
                                                unsigned short* __restrict__ Qb,
                                                unsigned short* __restrict__ Kb,
                                                unsigned short* __restrict__ VT) {
    int mt = blockIdx.x, z = blockIdx.y;
    int ten = z >> 2, b = z & 3;
    const float* A = (ten == 0 ? q : ten == 1 ? k : v) + (size_t)b * SEQ * DM;
    const unsigned short* W = Wt + (size_t)ten * DM * DM;
    const float* bias = ten == 0 ? bq : ten == 1 ? bk : bv;
    float scale = ten == 0 ? 0.07715167498104595f : 1.f;   // 1/sqrt(168)
    int m0 = mt * 64;

    // Al [0,8192) bf16 [64][64] swz; Bl [8192,73728) bf16 [512][64] swz.
    // Epilogue bounce Ol [64][520] u16 = 66,560 B reuses whole block.
    __shared__ __align__(16) char lds[73728];
    char* Al = lds;
    char* Bl = lds + 8192;

    int tid = threadIdx.x, lane = tid & 63, w = tid >> 6;
    int wn = w * 64;
    int l15 = lane & 15, g = lane >> 4;

    // A-stage: thread covers row ar=tid>>3, chunk acx=tid&7 (8 f32)
    int ar = tid >> 3, acx = tid & 7;
    int p_ = m0 + ar;
    int arow = p_ - PAD_; arow = arow < 0 ? 0 : (arow > SEQ - 1 ? SEQ - 1 : arow);
    const float* asrc = A + (size_t)arow * DM + acx * 8;
    char* adst = Al + ar * 128 + ((acx ^ (ar & 7)) << 4);

    float4v acc[4][4];
#pragma unroll
    for (int i = 0; i < 4; i++)
#pragma unroll
        for (int j = 0; j < 4; j++) { float4v zz = {0.f,0.f,0.f,0.f}; acc[i][j] = zz; }

    for (int kt = 0; kt < 8; kt++) {
        // --- B: 512 rows x 8 chunks via gload_lds, pre-swizzled source
#pragma unroll
        for (int it = 0; it < 8; it++) {
            int c = it * 512 + tid;
            int r = c >> 3;
            int kg = (c & 7) ^ (r & 7);
            gload16(W + (size_t)r * DM + kt * 64 + kg * 8, Bl + c * 16);
        }
        // --- A: 8 f32 -> bf16 -> one swizzled ds_write_b128
        {
            const float* src = asrc + kt * 64;
            float4v f0 = *(const float4v*)(src);
            float4v f1 = *(const float4v*)(src + 4);
            short8 h0;
            h0[0] = (short)bfc(f0.x); h0[1] = (short)bfc(f0.y);
            h0[2] = (short)bfc(f0.z); h0[3] = (short)bfc(f0.w);
            h0[4] = (short)bfc(f1.x); h0[5] = (short)bfc(f1.y);
            h0[6] = (short)bfc(f1.z); h0[7] = (short)bfc(f1.w);
            *(short8*)(adst) = h0;
        }
        __syncthreads();
#pragma unroll
        for (int ks = 0; ks < 2; ks++) {
            short8 af[4], bfr[4];
#pragma unroll
            for (int i = 0; i < 4; i++) {
                int r = i * 16 + l15, kg = ks * 4 + g;
                af[i] = *(const short8*)(Al + r * 128 + ((kg ^ (r & 7)) << 4));
            }
#pragma unroll
            for (int j = 0; j < 4; j++) {
                int r = wn + j * 16 + l15, kg = ks * 4 + g;
                bfr[j] = *(const short8*)(Bl + r * 128 + ((kg ^ (r & 7)) << 4));
            }
#pragma unroll
            for (int i = 0; i < 4; i++)
#pragma unroll
                for (int j = 0; j < 4; j++)
                    acc[i][j] = MFMA16(af[i], bfr[j], acc[i][j], 0, 0, 0);
        }
        __syncthreads();
    }

    if (ten <= 1) {
        // bounce [64][520] u16 then coalesced short8 head-split writes
        unsigned short* Ol = (unsigned short*)lds;
#pragma unroll
        for (int j = 0; j < 4; j++) {
            int n = wn + j * 16 + l15;
            float bval = bias[n];
#pragma unroll
            for (int i = 0; i < 4; i++) {
                float4v vv = acc[i][j];
#pragma unroll
                for (int r = 0; r < 4; r++)
                    Ol[(i * 16 + g * 4 + r) * 520 + n] = f2bf((vv[r] + bval) * scale);
            }
        }
        __syncthreads();
        unsigned short* O = ten == 0 ? Qb : Kb;
        for (int c = tid; c < 4096; c += 512) {        // 64 rows x 64 chunks
            int row = c >> 6, n8 = c & 63;
            int p = m0 + row;
            if (p < KP) {
                int h = n8 >> 3, ch = n8 & 7;
                *(short8*)(O + ((size_t)(h * BATCH + b) * KP + p) * 64 + ch * 8) =
                    *(const short8*)(Ol + row * 520 + n8 * 8);
            }
        }
    } else {
        // V: direct transposed stores VT[hb][d][p] (lane has 4 consecutive p)
#pragma unroll
        for (int j = 0; j < 4; j++) {
            int n = wn + j * 16 + l15;
            float bval = bias[n];
            int h = n >> 6, d = n & 63;
            unsigned short* base = VT + ((size_t)(h * BATCH + b) * 64 + d) * KP;
#pragma unroll
            for (int i = 0; i < 4; i++) {
                int p = m0 + i * 16 + g * 4;
                if (p <= KP - 4) {
                    float4v vv = acc[i][j];
                    ushort4v wv;
                    wv[0] = f2bf(vv.x + bval); wv[1] = f2bf(vv.y + bval);
                    wv[2] = f2bf(vv.z + bval); wv[3] = f2bf(vv.w + bval);
                    *(ushort4v*)(base + p) = wv;
                }
            }
        }
    }
}

// ============ kernel 2: windowed causal attention ============================
__global__ __launch_bounds__(384) void kattn(const unsigned short* __restrict__ Qb,
                                             const unsigned short* __restrict__ Kb,
                                             const unsigned short* __restrict__ VT,
                                             unsigned short* __restrict__ attn) {
    int win = blockIdx.x, hb = blockIdx.y;
    int h = hb >> 2, b = hb & 3;
    const unsigned short* Qg = Qb + (size_t)hb * KP * 64;
    const unsigned short* Kg = Kb + (size_t)hb * KP * 64;
    const unsigned short* Vt = VT + (size_t)hb * 64 * KP;
    int p0 = win * STEP_;

    // Ql [0,12288) 96x64; Kl [12288,28672) 128x64; Vl [28672,45056) 64x128;
    // Pl [45056,69632) 96x128. Ol reuses Ql.
    __shared__ __align__(16) char lds[69632];

    int tid = threadIdx.x, lane = tid & 63, f = tid >> 6;
    int l15 = lane & 15, g = lane >> 4;

#pragma unroll
    for (int it = 0; it < 5; it++) {
        int base = it * 384 + f * 64;
        if (base < 768) {                       // Q chunks
            int c = base + lane;
            int qi = c >> 3, kg = (c & 7) ^ (qi & 7);
            gload16(Qg + (size_t)(p0 + PAD_ + qi) * 64 + kg * 8, lds + base * 16);
        } else if (base < 1792) {               // K chunks
            int c = base + lane - 768;
            int x = c >> 3, kg = (c & 7) ^ (x & 7);
            gload16(Kg + (size_t)(p0 + x) * 64 + kg * 8, lds + base * 16);
        }
    }
    for (int c = tid; c < 2048; c += 384) {
        int d = c >> 5, c2 = c & 31;
        ushort4v wv = *(const ushort4v*)(Vt + (size_t)d * KP + p0 + c2 * 4);
        int cx = c2 >> 1;
        *(ushort4v*)(lds + 28672 + d * 256 + (((cx ^ (d & 7)) << 4) | ((c2 & 1) * 8))) = wv;
    }
    __syncthreads();

    short8 bq2[2];
    {
        int r = f * 16 + l15;
#pragma unroll
        for (int ks = 0; ks < 2; ks++) {
            int kg = ks * 4 + g;
            bq2[ks] = *(const short8*)(lds + r * 128 + ((kg ^ (r & 7)) << 4));
        }
    }
    float4v st[8];
#pragma unroll
    for (int xf = 0; xf < 8; xf++) {
        float4v zz = {0.f,0.f,0.f,0.f}; st[xf] = zz;
#pragma unroll
        for (int ks = 0; ks < 2; ks++) {
            int r = xf * 16 + l15;
            int kg = ks * 4 + g;
            short8 a = *(const short8*)(lds + 12288 + r * 128 + ((kg ^ (r & 7)) << 4));
            st[xf] = MFMA16(a, bq2[ks], st[xf], 0, 0, 0);
        }
    }

    int w_abs = PAD_ + f * 16 + l15;
    int w_eff = w_abs > 125 ? 125 : w_abs;
    float mx = -1e30f;
#pragma unroll
    for (int xf = 0; xf < 8; xf++)
#pragma unroll
        for (int r = 0; r < 4; r++) {
            int x = xf * 16 + g * 4 + r;
            float vv = st[xf][r];
            if (x > w_eff) vv = -1e30f;
            st[xf][r] = vv;
            mx = fmaxf(mx, vv);
        }
    mx = fmaxf(mx, __shfl_xor(mx, 16));
    mx = fmaxf(mx, __shfl_xor(mx, 32));
    float s = 0.f;
#pragma unroll
    for (int xf = 0; xf < 8; xf++)
#pragma unroll
        for (int r = 0; r < 4; r++) {
            float e = __expf(st[xf][r] - mx);
            st[xf][r] = e;
            s += e;
        }
    s += __shfl_xor(s, 16);
    s += __shfl_xor(s, 32);
    float inv = 1.f / s;

    {
        int qi = f * 16 + l15;
#pragma unroll
        for (int xf = 0; xf < 8; xf++) {
            ushort4v pw;
#pragma unroll
            for (int r = 0; r < 4; r++) pw[r] = f2bf(st[xf][r] * inv);
            int xc = 2 * xf + (g >> 1);
            *(ushort4v*)(lds + 45056 + qi * 256 + ((xc ^ (qi & 7)) << 4) + (g & 1) * 8) = pw;
        }
    }
    __syncthreads();

    float4v pv[4];
#pragma unroll
    for (int j = 0; j < 4; j++) { float4v zz = {0.f,0.f,0.f,0.f}; pv[j] = zz; }
    int qi = f * 16 + l15;
#pragma unroll
    for (int g2 = 0; g2 < 4; g2++) {
        int xc = g2 * 4 + g;
        short8 a = *(const short8*)(lds + 45056 + qi * 256 + ((xc ^ (qi & 7)) << 4));
#pragma unroll
        for (int j = 0; j < 4; j++) {
            int d = j * 16 + l15;
            short8 bvv = *(const short8*)(lds + 28672 + d * 256 + ((xc ^ (d & 7)) << 4));
            pv[j] = MFMA16(a, bvv, pv[j], 0, 0, 0);
        }
    }

    unsigned short* Ol = (unsigned short*)lds;
#pragma unroll
    for (int j = 0; j < 4; j++) {
        int d = j * 16 + l15;
#pragma unroll
        for (int r = 0; r < 4; r++) {
            int qq = f * 16 + g * 4 + r;
            int byte = qq * 128 + ((((d >> 3) ^ (qq & 7))) << 4) + (d & 7) * 2;
            *(unsigned short*)((char*)Ol + byte) = f2bf(pv[j][r]);
        }
    }
    __syncthreads();
    for (int c = tid; c < 672; c += 384) {
        int qq = c >> 3, ch = c & 7;
        short8 hv = *(const short8*)((char*)Ol + qq * 128 + ((ch ^ (qq & 7)) << 4));
        size_t off = ((size_t)(b * SEQ + win * STEP_ + qq) * DM) + h * 64 + ch * 8;
        *(short8*)(attn + off) = hv;
    }
}

// ============ kernel 3: output projection, m97 128x128x64 ====================
__global__ __launch_bounds__(256) void kout(const unsigned short* __restrict__ Ab,
                                            const unsigned short* __restrict__ W,
                                            const float* __restrict__ bias,
                                            float* __restrict__ Out) {
    int m0 = blockIdx.x * 128, n0 = blockIdx.y * 128;
    __shared__ __align__(16) char lds[32768];
    char* Al = lds;
    char* Bl = lds + 16384;
    int tid = threadIdx.x, lane = tid & 63, w = tid >> 6;
    int wm = (w >> 1) * 64, wn = (w & 1) * 64;
    int l15 = lane & 15, g = lane >> 4;

    float4v acc[4][4];
#pragma unroll
    for (int i = 0; i < 4; i++)
#pragma unroll
        for (int j = 0; j < 4; j++) { float4v zz = {0.f,0.f,0.f,0.f}; acc[i][j] = zz; }

    for (int kt = 0; kt < 8; kt++) {
#pragma unroll
        for (int it = 0; it < 4; it++) {
            int c = it * 256 + tid;
            int r = c >> 3;
            int kg = (c & 7) ^ (r & 7);
            int row = m0 + r; if (row > MROWS - 1) row = MROWS - 1;
            gload16(Ab + (size_t)row * DM + kt * 64 + kg * 8, Al + c * 16);
        }
#pragma unroll
        for (int it = 0; it < 4; it++) {
            int c = it * 256 + tid;
            int r = c >> 3;
            int kg = (c & 7) ^ (r & 7);
            gload16(W + (size_t)(n0 + r) * DM + kt * 64 + kg * 8, Bl + c * 16);
        }
        __syncthreads();
#pragma unroll
        for (int ks = 0; ks < 2; ks++) {
            short8 af[4], bfr[4];
#pragma unroll
            for (int i = 0; i < 4; i++) {
                int r = wm + i * 16 + l15, kg = ks * 4 + g;
                af[i] = *(const short8*)(Al + r * 128 + ((kg ^ (r & 7)) << 4));
            }
#pragma unroll
            for (int j = 0; j < 4; j++) {
                int r = wn + j * 16 + l15, kg = ks * 4 + g;
                bfr[j] = *(const short8*)(Bl + r * 128 + ((kg ^ (r & 7)) << 4));
            }
#pragma unroll
            for (int i = 0; i < 4; i++)
#pragma unroll
                for (int j = 0; j < 4; j++)
                    acc[i][j] = MFMA16(af[i], bfr[j], acc[i][j], 0, 0, 0);
        }
        __syncthreads();
    }
#pragma unroll
    for (int j = 0; j < 4; j++) {
        int n = n0 + wn + j * 16 + l15;
        float bv = bias[n];
#pragma unroll
        for (int i = 0; i < 4; i++) {
            float4v vv = acc[i][j];
#pragma unroll
            for (int r = 0; r < 4; r++) {
                int m = m0 + wm + i * 16 + g * 4 + r;
                if (m < MROWS) Out[(size_t)m * DM + n] = vv[r] + bv;
            }
        }
    }
}

// ============ launch =========================================================
extern "C" void kernel_launch(void* const* d_in, const int* in_sizes, int n_in,
                              void* d_out, int out_size, void* d_ws, size_t ws_size,
                              hipStream_t stream) {
    const float* q  = (const float*)d_in[0];
    const float* k  = (const float*)d_in[1];
    const float* v  = (const float*)d_in[2];
    const float* Wq = (const float*)d_in[3];
    const float* bq = (const float*)d_in[4];
    const float* Wk = (const float*)d_in[5];
    const float* bk = (const float*)d_in[6];
    const float* Wv = (const float*)d_in[7];
    const float* bv = (const float*)d_in[8];
    const float* Wo = (const float*)d_in[9];
    const float* bo = (const float*)d_in[10];

    const size_t WT_ELEMS  = (size_t)4 * DM * DM;
    const size_t QKV_ELEMS = (size_t)32 * KP * 64;
    const size_t ATT_ELEMS = (size_t)MROWS * DM;
    size_t need = (WT_ELEMS + 3 * QKV_ELEMS + ATT_ELEMS) * 2;
    if (ws_size < need) return;

    unsigned short* Wt = (unsigned short*)d_ws;
    unsigned short* Qb = Wt + WT_ELEMS;
    unsigned short* Kb = Qb + QKV_ELEMS;
    unsigned short* VT = Kb + QKV_ELEMS;
    unsigned short* Ab = VT + QKV_ELEMS;

    kprep<<<dim3(8, 8, 4), dim3(256), 0, stream>>>(Wq, Wk, Wv, Wo, Wt);
    kproj<<<dim3(133, 12), dim3(512), 0, stream>>>(q, k, v, Wt, bq, bk, bv,
                                                   Qb, Kb, VT);
    kattn<<<dim3(NWIN, 32), dim3(384), 0, stream>>>(Qb, Kb, VT, Ab);
    kout<<<dim3(263, 4), dim3(256), 0, stream>>>(Ab, Wt + 3 * DM * DM, bo,
                                                 (float*)d_out);
}